// Round 12
// baseline (100.890 us; speedup 1.0000x reference)
//
#include <hip/hip_runtime.h>
#include <hip/hip_fp16.h>

#define N_NODES 50000
#define DIM 128
#define NEDGE 800000
#define NGRAPH 100
#define NPG 500      // nodes per graph
#define NBUCKET 250  // dst buckets
#define NPB 200      // nodes per bucket
#define BCAP 4096    // padded slots per bucket
#define CHUNK 4096   // edges per scatter chunk
#define EPT (CHUNK / 256)

typedef _Float16 f16x8 __attribute__((ext_vector_type(8)));
typedef float f32x4 __attribute__((ext_vector_type(4)));
typedef float f32x2 __attribute__((ext_vector_type(2)));

// ---------------- fp8 helpers (OCP e4m3 HW converts) ----------------
__device__ inline float wgt(unsigned p) {
    return __half2float(__ushort_as_half((unsigned short)(p & 0xffffu)));
}
// accumulate 16 fp8 features (16 B) scaled by w into acc[16]
__device__ inline void accrow16(uint4 q, float w, float* acc) {
    f32x2 f;
    f = __builtin_amdgcn_cvt_pk_f32_fp8((int)q.x, false); acc[0]  = fmaf(w, f[0], acc[0]);  acc[1]  = fmaf(w, f[1], acc[1]);
    f = __builtin_amdgcn_cvt_pk_f32_fp8((int)q.x, true);  acc[2]  = fmaf(w, f[0], acc[2]);  acc[3]  = fmaf(w, f[1], acc[3]);
    f = __builtin_amdgcn_cvt_pk_f32_fp8((int)q.y, false); acc[4]  = fmaf(w, f[0], acc[4]);  acc[5]  = fmaf(w, f[1], acc[5]);
    f = __builtin_amdgcn_cvt_pk_f32_fp8((int)q.y, true);  acc[6]  = fmaf(w, f[0], acc[6]);  acc[7]  = fmaf(w, f[1], acc[7]);
    f = __builtin_amdgcn_cvt_pk_f32_fp8((int)q.z, false); acc[8]  = fmaf(w, f[0], acc[8]);  acc[9]  = fmaf(w, f[1], acc[9]);
    f = __builtin_amdgcn_cvt_pk_f32_fp8((int)q.z, true);  acc[10] = fmaf(w, f[0], acc[10]); acc[11] = fmaf(w, f[1], acc[11]);
    f = __builtin_amdgcn_cvt_pk_f32_fp8((int)q.w, false); acc[12] = fmaf(w, f[0], acc[12]); acc[13] = fmaf(w, f[1], acc[13]);
    f = __builtin_amdgcn_cvt_pk_f32_fp8((int)q.w, true);  acc[14] = fmaf(w, f[0], acc[14]); acc[15] = fmaf(w, f[1], acc[15]);
}

// ---------------- prep: cursor init + pre-swizzled fp16 W-fragments -------
__global__ void prep(const float* __restrict__ W1, const float* __restrict__ W2,
                     _Float16* __restrict__ fragW1, _Float16* __restrict__ fragW2,
                     int* __restrict__ gCur) {
    const int b = blockIdx.x;
    if (b == 128) {
        int t = threadIdx.x;
        if (t < NBUCKET) gCur[t] = t * BCAP;
        return;
    }
    const float* W = (b < 64) ? W1 : W2;
    _Float16* F = (b < 64) ? fragW1 : fragW2;
    int idx = (b & 63) * 256 + threadIdx.x;   // 0..16383
    int j = idx & 7, l = (idx >> 3) & 63, kt = (idx >> 9) & 3, nt = idx >> 11;
    int k = kt * 32 + ((l >> 4) << 3) + j;
    int col = (nt << 4) + (l & 15);
    F[idx] = (_Float16)W[k * DIM + col];
}

// ---------------- pass 1: bucket edges by dst/NPB --------------
__global__ void bucket_scatter(const int* __restrict__ src, const int* __restrict__ dst,
                               const float* __restrict__ w, int* __restrict__ gCur,
                               uint2* __restrict__ stage, int E) {
    __shared__ int hist[NBUCKET];
    __shared__ int base[NBUCKET];
    for (int i = threadIdx.x; i < NBUCKET; i += 256) hist[i] = 0;
    __syncthreads();
    const int e0 = blockIdx.x * CHUNK;
    int myDst[EPT];
#pragma unroll
    for (int j = 0; j < EPT; ++j) {
        int e = e0 + j * 256 + threadIdx.x;
        int d = (e < E) ? dst[e] : -1;
        myDst[j] = d;
        if (d >= 0) atomicAdd(&hist[d / NPB], 1);
    }
    __syncthreads();
    for (int i = threadIdx.x; i < NBUCKET; i += 256)
        base[i] = atomicAdd(&gCur[i], hist[i]);   // reserve private run
    __syncthreads();
#pragma unroll
    for (int j = 0; j < EPT; ++j) {
        int d = myDst[j];
        if (d >= 0) {
            int e = e0 + j * 256 + threadIdx.x;
            int b = d / NPB;
            int p = atomicAdd(&base[b], 1);
            unsigned short wh = __half_as_ushort(__float2half_rn(w[e]));
            stage[p] = make_uint2(((unsigned)src[e] << 16) | (unsigned)wh,
                                  (unsigned)(d - b * NPB));
        }
    }
}

// ---------------- MFMA fragment loads ----------------
__device__ inline f16x8 load_afrag_f32(const float* a) {
    float4 u0 = *(const float4*)a;
    float4 u1 = *(const float4*)(a + 4);
    f16x8 r;
    r[0] = (_Float16)u0.x; r[1] = (_Float16)u0.y; r[2] = (_Float16)u0.z; r[3] = (_Float16)u0.w;
    r[4] = (_Float16)u1.x; r[5] = (_Float16)u1.y; r[6] = (_Float16)u1.z; r[7] = (_Float16)u1.w;
    return r;
}

// one 128-row gemm tile from fp32 A, fragW in LDS (8 waves x 16 rows)
__device__ inline void gemm_tile_f32(const float* __restrict__ A, const _Float16* fragW,
                                     unsigned char* __restrict__ C, int blk, int tid) {
    const int lane = tid & 63;
    const int wid = tid >> 6;
    const int row0 = blk * 128 + wid * 16;
    if (row0 >= N_NODES) return;
    const int arow = row0 + (lane & 15);
    const int koff = (lane >> 4) << 3;
    f32x4 acc[8] = {};
#pragma unroll
    for (int kt = 0; kt < 4; ++kt) {
        f16x8 a = load_afrag_f32(A + (size_t)arow * DIM + kt * 32 + koff);
#pragma unroll
        for (int nt = 0; nt < 8; ++nt) {
            f16x8 b = *(const f16x8*)&fragW[(((nt << 2) | kt) << 9) | (lane << 3)];
            acc[nt] = __builtin_amdgcn_mfma_f32_16x16x32_f16(a, b, acc[nt], 0, 0, 0);
        }
    }
    const int crow = row0 + ((lane >> 4) << 2);
    const int ccol = lane & 15;
#pragma unroll
    for (int nt = 0; nt < 8; ++nt) {
#pragma unroll
        for (int r = 0; r < 4; ++r) {
            int v8 = __builtin_amdgcn_cvt_pk_fp8_f32(acc[nt][r], acc[nt][r], 0, false);
            C[(size_t)(crow + r) * DIM + (nt << 4) + ccol] = (unsigned char)(v8 & 0xff);
        }
    }
}

// ---------------- fused: gemm1 (blocks < MB) + bucket_build (blocks >= MB) -
#define MFMA_BLK ((N_NODES + 127) / 128)   // 391
__global__ __launch_bounds__(512) void gemm1_build(
        const float* __restrict__ A, const _Float16* __restrict__ fragWg,
        unsigned char* __restrict__ C, const int* __restrict__ gCur,
        const uint2* __restrict__ stage, unsigned int* __restrict__ pack,
        int2* __restrict__ range) {
    __shared__ __align__(16) _Float16 fragW[16384];   // 32 KB (gemm path)
    __shared__ int lhist[NPB];
    __shared__ int lincl[256];
    __shared__ int lcur[NPB];
    const int tid = threadIdx.x;
    if (blockIdx.x < MFMA_BLK) {
        for (int i = tid; i < 2048; i += 512)
            ((uint4*)fragW)[i] = ((const uint4*)fragWg)[i];
        __syncthreads();
        gemm_tile_f32(A, fragW, C, blockIdx.x, tid);
        return;
    }
    // ---- bucket_build path (512 threads, 8 items each) ----
    const int b = blockIdx.x - MFMA_BLK;
    const int t = tid;
    const int cnt = gCur[b] - b * BCAP;
    for (int i = t; i < NPB; i += 512) lhist[i] = 0;
    __syncthreads();
    unsigned myX[BCAP / 512];
    int myLd[BCAP / 512];
#pragma unroll
    for (int j = 0; j < BCAP / 512; ++j) {
        int i = j * 512 + t;
        if (i < cnt) {
            uint2 r = stage[b * BCAP + i];
            myX[j] = r.x;
            myLd[j] = (int)r.y;
            atomicAdd(&lhist[r.y], 1);
        } else {
            myLd[j] = -1;
        }
    }
    __syncthreads();
    int h = (t < NPB) ? lhist[t] : 0;
    if (t < 256) lincl[t] = h;
    __syncthreads();
    for (int off = 1; off < 256; off <<= 1) {
        int v = (t >= off && t < 256) ? lincl[t - off] : 0;
        __syncthreads();
        if (t < 256) lincl[t] += v;
        __syncthreads();
    }
    if (t < NPB) lcur[t] = lincl[t] - h;   // exclusive prefix
    __syncthreads();
#pragma unroll
    for (int j = 0; j < BCAP / 512; ++j) {
        if (myLd[j] >= 0) {
            int p = atomicAdd(&lcur[myLd[j]], 1);
            pack[b * BCAP + p] = myX[j];
        }
    }
    if (t < NPB) {
        int v = b * NPB + t;
        range[v] = make_int2(b * BCAP + lincl[t] - h, b * BCAP + lincl[t]);
    }
}

// ---------------- shared gather core: 8 lanes x uint4 (16 fp8) ------------
__device__ inline void gather_core(const unsigned char* __restrict__ msg,
                                   const unsigned int* __restrict__ pack,
                                   int beg, int end, int lane8, float* acc) {
    int i = beg;
    for (; i + 7 < end; i += 8) {      // 8 independent gather chains
        unsigned p[8];
        uint4 q[8];
#pragma unroll
        for (int j = 0; j < 8; ++j) p[j] = pack[i + j];
#pragma unroll
        for (int j = 0; j < 8; ++j)
            q[j] = ((const uint4*)(msg + (size_t)(p[j] >> 16) * DIM))[lane8];
#pragma unroll
        for (int j = 0; j < 8; ++j) accrow16(q[j], wgt(p[j]), acc);
    }
    for (; i + 3 < end; i += 4) {
        unsigned p0 = pack[i], p1 = pack[i + 1], p2 = pack[i + 2], p3 = pack[i + 3];
        uint4 q0 = ((const uint4*)(msg + (size_t)(p0 >> 16) * DIM))[lane8];
        uint4 q1 = ((const uint4*)(msg + (size_t)(p1 >> 16) * DIM))[lane8];
        uint4 q2 = ((const uint4*)(msg + (size_t)(p2 >> 16) * DIM))[lane8];
        uint4 q3 = ((const uint4*)(msg + (size_t)(p3 >> 16) * DIM))[lane8];
        accrow16(q0, wgt(p0), acc);
        accrow16(q1, wgt(p1), acc);
        accrow16(q2, wgt(p2), acc);
        accrow16(q3, wgt(p3), acc);
    }
    for (; i < end; ++i) {
        unsigned p = pack[i];
        uint4 q = ((const uint4*)(msg + (size_t)(p >> 16) * DIM))[lane8];
        accrow16(q, wgt(p), acc);
    }
}

// ---------------- fused gather0 + gemm2 ----------------
// Block = 32 nodes (32 groups x 8 lanes). Phase A: gather h1 rows ->
// LDS fp16 tile (XOR-swizzled). Phase B: 4 waves, two 16-row MFMA tiles
// vs fragW2 (global, L1-hot) -> fp8 C.
__global__ __launch_bounds__(256) void gather_gemm2(
        const unsigned char* __restrict__ msg, const unsigned int* __restrict__ pack,
        const int2* __restrict__ range, const float* __restrict__ bias,
        const _Float16* __restrict__ fragW2, unsigned char* __restrict__ C) {
    __shared__ __align__(16) char hT[32 * 256];   // 32 rows x 128 fp16 (8 KB)
    const int t = threadIdx.x;
    const int grpL = t >> 3;       // local node 0..31
    const int lane8 = t & 7;
    const int tile = blockIdx.x;   // 1563 tiles x 32 nodes
    const int grp = tile * 32 + grpL;
    if (grp < N_NODES) {
        int2 r = range[grp];
        float acc[16] = {};
        gather_core(msg, pack, r.x, r.y, lane8, acc);
        float4 b0 = ((const float4*)bias)[4 * lane8 + 0];
        float4 b1 = ((const float4*)bias)[4 * lane8 + 1];
        float4 b2 = ((const float4*)bias)[4 * lane8 + 2];
        float4 b3 = ((const float4*)bias)[4 * lane8 + 3];
        union { __half2 h[8]; uint4 u[2]; } o;
        o.h[0] = __floats2half2_rn(fmaxf(acc[0]  + b0.x, 0.f), fmaxf(acc[1]  + b0.y, 0.f));
        o.h[1] = __floats2half2_rn(fmaxf(acc[2]  + b0.z, 0.f), fmaxf(acc[3]  + b0.w, 0.f));
        o.h[2] = __floats2half2_rn(fmaxf(acc[4]  + b1.x, 0.f), fmaxf(acc[5]  + b1.y, 0.f));
        o.h[3] = __floats2half2_rn(fmaxf(acc[6]  + b1.z, 0.f), fmaxf(acc[7]  + b1.w, 0.f));
        o.h[4] = __floats2half2_rn(fmaxf(acc[8]  + b2.x, 0.f), fmaxf(acc[9]  + b2.y, 0.f));
        o.h[5] = __floats2half2_rn(fmaxf(acc[10] + b2.z, 0.f), fmaxf(acc[11] + b2.w, 0.f));
        o.h[6] = __floats2half2_rn(fmaxf(acc[12] + b3.x, 0.f), fmaxf(acc[13] + b3.y, 0.f));
        o.h[7] = __floats2half2_rn(fmaxf(acc[14] + b3.z, 0.f), fmaxf(acc[15] + b3.w, 0.f));
        int base = (grpL << 8) | (lane8 << 5);
        int m = (grpL & 7) << 4;               // XOR swizzle (G4)
        *(uint4*)(hT + ((base) ^ m)) = o.u[0];
        *(uint4*)(hT + ((base + 16) ^ m)) = o.u[1];
    }
    __syncthreads();
    // ---- MFMA phase: wave wid -> row-tile rt=wid>>1, col-tiles ntBase..+3 --
    const int lane = t & 63;
    const int wid = t >> 6;
    const int rt = wid >> 1;
    const int ntBase = (wid & 1) << 2;
    const int arow = rt * 16 + (lane & 15);
    const int koff = (lane >> 4) << 3;
    f32x4 acc2[4] = {};
#pragma unroll
    for (int kt = 0; kt < 4; ++kt) {
        int boff = (arow << 8) | (((kt << 5) + koff) << 1);
        boff ^= (arow & 7) << 4;
        f16x8 a = *(const f16x8*)(hT + boff);
#pragma unroll
        for (int n = 0; n < 4; ++n) {
            int nt = ntBase + n;
            f16x8 b = *(const f16x8*)&fragW2[(((nt << 2) | kt) << 9) | (lane << 3)];
            acc2[n] = __builtin_amdgcn_mfma_f32_16x16x32_f16(a, b, acc2[n], 0, 0, 0);
        }
    }
    const int rowBase = tile * 32 + rt * 16;
    if (rowBase < N_NODES) {                   // tail tile guard
        const int crow = rowBase + ((lane >> 4) << 2);
        const int ccol = lane & 15;
#pragma unroll
        for (int n = 0; n < 4; ++n) {
#pragma unroll
            for (int r = 0; r < 4; ++r) {
                int v8 = __builtin_amdgcn_cvt_pk_fp8_f32(acc2[n][r], acc2[n][r], 0, false);
                C[(size_t)(crow + r) * DIM + ((ntBase + n) << 4) + ccol] = (unsigned char)(v8 & 0xff);
            }
        }
    }
}

// ---------------- gather1: s = relu(A(h1@W2)+b2) @ Wf ----------------
__global__ void gather_wf(const unsigned char* __restrict__ msg,
                          const unsigned int* __restrict__ pack,
                          const int2* __restrict__ range, const float* __restrict__ bias,
                          const float* __restrict__ wf, float* __restrict__ outS) {
    int gid = blockIdx.x * blockDim.x + threadIdx.x;
    int grp = gid >> 3, lane8 = gid & 7;
    if (grp >= N_NODES) return;
    int2 r = range[grp];
    float acc[16] = {};
    gather_core(msg, pack, r.x, r.y, lane8, acc);
    float4 b0 = ((const float4*)bias)[4 * lane8 + 0];
    float4 b1 = ((const float4*)bias)[4 * lane8 + 1];
    float4 b2 = ((const float4*)bias)[4 * lane8 + 2];
    float4 b3 = ((const float4*)bias)[4 * lane8 + 3];
    float4 f0 = ((const float4*)wf)[4 * lane8 + 0];
    float4 f1 = ((const float4*)wf)[4 * lane8 + 1];
    float4 f2 = ((const float4*)wf)[4 * lane8 + 2];
    float4 f3 = ((const float4*)wf)[4 * lane8 + 3];
    float d = fmaxf(acc[0]  + b0.x, 0.f) * f0.x + fmaxf(acc[1]  + b0.y, 0.f) * f0.y
            + fmaxf(acc[2]  + b0.z, 0.f) * f0.z + fmaxf(acc[3]  + b0.w, 0.f) * f0.w
            + fmaxf(acc[4]  + b1.x, 0.f) * f1.x + fmaxf(acc[5]  + b1.y, 0.f) * f1.y
            + fmaxf(acc[6]  + b1.z, 0.f) * f1.z + fmaxf(acc[7]  + b1.w, 0.f) * f1.w
            + fmaxf(acc[8]  + b2.x, 0.f) * f2.x + fmaxf(acc[9]  + b2.y, 0.f) * f2.y
            + fmaxf(acc[10] + b2.z, 0.f) * f2.z + fmaxf(acc[11] + b2.w, 0.f) * f2.w
            + fmaxf(acc[12] + b3.x, 0.f) * f3.x + fmaxf(acc[13] + b3.y, 0.f) * f3.y
            + fmaxf(acc[14] + b3.z, 0.f) * f3.z + fmaxf(acc[15] + b3.w, 0.f) * f3.w;
#pragma unroll
    for (int off = 4; off; off >>= 1) d += __shfl_down(d, off, 8);
    if (lane8 == 0) outS[grp] = d;
}

// ---------------- fused final aggregation + per-graph readout -------------
__global__ void final_readout(const float* __restrict__ s, const unsigned int* __restrict__ pack,
                              const int2* __restrict__ range, const float* __restrict__ bfp,
                              float* __restrict__ out) {
    __shared__ float red[256];
    int g = blockIdx.x;
    float bf = bfp[0];
    float sum = 0.f;
    for (int n = threadIdx.x; n < NPG; n += blockDim.x) {
        int v = g * NPG + n;
        int2 r = range[v];
        float a = 0.f;
        for (int i = r.x; i < r.y; ++i) {
            unsigned int p = pack[i];
            a += wgt(p) * s[p >> 16];
        }
        a += bf;
        sum += 1.f / (1.f + expf(-a));
    }
    red[threadIdx.x] = sum;
    __syncthreads();
    for (int t = 128; t > 0; t >>= 1) {
        if (threadIdx.x < t) red[threadIdx.x] += red[threadIdx.x + t];
        __syncthreads();
    }
    if (threadIdx.x == 0) out[g] = red[0] / (float)NPG;
}

extern "C" void kernel_launch(void* const* d_in, const int* in_sizes, int n_in,
                              void* d_out, int out_size, void* d_ws, size_t ws_size,
                              hipStream_t stream) {
    const float* X  = (const float*)d_in[0];
    const float* ew = (const float*)d_in[1];
    const float* W1 = (const float*)d_in[2];
    const float* b1 = (const float*)d_in[3];
    const float* W2 = (const float*)d_in[4];
    const float* b2 = (const float*)d_in[5];
    const float* Wf = (const float*)d_in[6];
    const float* bf = (const float*)d_in[7];
    const int* ei   = (const int*)d_in[8];
    const int* src  = ei;
    const int* dst  = ei + NEDGE;

    float* out = (float*)d_out;

    // workspace layout
    char* ws = (char*)d_ws;
    size_t off = 0;
    unsigned char* bufA = (unsigned char*)(ws + off); off += (size_t)N_NODES * DIM;  // 6.4 MB
    unsigned char* bufB = (unsigned char*)(ws + off); off += (size_t)N_NODES * DIM;  // 6.4 MB
    uint2* stage = (uint2*)(ws + off);  off += (size_t)NBUCKET * BCAP * 8;           // 8 MB
    unsigned int* pack = (unsigned int*)(ws + off); off += (size_t)NBUCKET * BCAP * 4; // 4 MB
    int2* range = (int2*)(ws + off);    off += (size_t)N_NODES * 8;                  // 400 KB
    int* gCur   = (int*)(ws + off);     off += (size_t)256 * 4;
    _Float16* fragW1 = (_Float16*)(ws + off); off += (size_t)16384 * 2;              // 32 KB
    _Float16* fragW2 = (_Float16*)(ws + off); off += (size_t)16384 * 2;              // 32 KB
    float* s_node = (float*)(ws + off); off += (size_t)N_NODES * 4;

    const int TB = 256;
    const int SCAT_BLK = (NEDGE + CHUNK - 1) / CHUNK;     // 196
    const int TILE_BLK = (N_NODES + 31) / 32;             // 1563
    const int GATHER_BLK = (N_NODES * 8 + TB - 1) / TB;   // 1563

    // ---- prep: cursors + pre-swizzled W fragments ----
    prep<<<129, TB, 0, stream>>>(W1, W2, fragW1, fragW2, gCur);
    // ---- CSR pass 1 ----
    bucket_scatter<<<SCAT_BLK, TB, 0, stream>>>(src, dst, ew, gCur, stage, NEDGE);
    // ---- layer-1 GEMM fused with CSR pass 2 (independent work) ----
    gemm1_build<<<MFMA_BLK + NBUCKET, 512, 0, stream>>>(X, fragW1, bufA, gCur,
                                                        stage, pack, range);
    // ---- fused: gather0 (h1) + gemm2 (h1@W2 -> bufB fp8) ----
    gather_gemm2<<<TILE_BLK, TB, 0, stream>>>(bufA, pack, range, b1, fragW2, bufB);
    // ---- gather1 + Wf dot -> s_node ----
    gather_wf<<<GATHER_BLK, TB, 0, stream>>>(bufB, pack, range, b2, Wf, s_node);
    // ---- final aggregation + readout (fused) ----
    final_readout<<<NGRAPH, TB, 0, stream>>>(s_node, pack, range, bf, out);
}

// Round 13
// 100.511 us; speedup vs baseline: 1.0038x; 1.0038x over previous
//
#include <hip/hip_runtime.h>
#include <hip/hip_fp16.h>

#define N_NODES 50000
#define DIM 128
#define NEDGE 800000
#define NGRAPH 100
#define NPG 500      // nodes per graph
#define NBUCKET 250  // dst buckets
#define NPB 200      // nodes per bucket
#define BCAP 4096    // padded slots per bucket
#define CHUNK 4096   // edges per scatter chunk
#define EPT (CHUNK / 256)
#define SCAT_BLK ((NEDGE + CHUNK - 1) / CHUNK)   // 196

typedef _Float16 f16x8 __attribute__((ext_vector_type(8)));
typedef float f32x4 __attribute__((ext_vector_type(4)));
typedef float f32x2 __attribute__((ext_vector_type(2)));

// ---------------- fp8 helpers (OCP e4m3 HW converts) ----------------
__device__ inline float wgt(unsigned p) {
    return __half2float(__ushort_as_half((unsigned short)(p & 0xffffu)));
}
__device__ inline void accrow(uint2 q, float w, float* acc) {
    f32x2 f;
    f = __builtin_amdgcn_cvt_pk_f32_fp8((int)q.x, false); acc[0] = fmaf(w, f[0], acc[0]); acc[1] = fmaf(w, f[1], acc[1]);
    f = __builtin_amdgcn_cvt_pk_f32_fp8((int)q.x, true);  acc[2] = fmaf(w, f[0], acc[2]); acc[3] = fmaf(w, f[1], acc[3]);
    f = __builtin_amdgcn_cvt_pk_f32_fp8((int)q.y, false); acc[4] = fmaf(w, f[0], acc[4]); acc[5] = fmaf(w, f[1], acc[5]);
    f = __builtin_amdgcn_cvt_pk_f32_fp8((int)q.y, true);  acc[6] = fmaf(w, f[0], acc[6]); acc[7] = fmaf(w, f[1], acc[7]);
}

// ---------------- pass 1: bucket scatter + fragW build (fused) ------------
// blocks 0..SCAT_BLK-1: scatter edges; blocks SCAT_BLK..SCAT_BLK+127: build
// pre-swizzled fp16 W fragments. gCur must be zeroed (hipMemsetAsync).
__global__ void scatter_prep(const int* __restrict__ src, const int* __restrict__ dst,
                             const float* __restrict__ w, int* __restrict__ gCur,
                             uint2* __restrict__ stage, const float* __restrict__ W1,
                             const float* __restrict__ W2, _Float16* __restrict__ fragW1,
                             _Float16* __restrict__ fragW2, int E) {
    if (blockIdx.x >= SCAT_BLK) {
        const int b = blockIdx.x - SCAT_BLK;   // 0..127
        const float* W = (b < 64) ? W1 : W2;
        _Float16* F = (b < 64) ? fragW1 : fragW2;
        int idx = (b & 63) * 256 + threadIdx.x;   // 0..16383
        int j = idx & 7, l = (idx >> 3) & 63, kt = (idx >> 9) & 3, nt = idx >> 11;
        int k = kt * 32 + ((l >> 4) << 3) + j;
        int col = (nt << 4) + (l & 15);
        F[idx] = (_Float16)W[k * DIM + col];
        return;
    }
    __shared__ int hist[NBUCKET];
    __shared__ int base[NBUCKET];
    for (int i = threadIdx.x; i < NBUCKET; i += 256) hist[i] = 0;
    __syncthreads();
    const int e0 = blockIdx.x * CHUNK;
    int myDst[EPT];
#pragma unroll
    for (int j = 0; j < EPT; ++j) {
        int e = e0 + j * 256 + threadIdx.x;
        int d = (e < E) ? dst[e] : -1;
        myDst[j] = d;
        if (d >= 0) atomicAdd(&hist[d / NPB], 1);
    }
    __syncthreads();
    for (int i = threadIdx.x; i < NBUCKET; i += 256)
        base[i] = i * BCAP + atomicAdd(&gCur[i], hist[i]);   // zero-based cursors
    __syncthreads();
#pragma unroll
    for (int j = 0; j < EPT; ++j) {
        int d = myDst[j];
        if (d >= 0) {
            int e = e0 + j * 256 + threadIdx.x;
            int b = d / NPB;
            int p = atomicAdd(&base[b], 1);
            unsigned short wh = __half_as_ushort(__float2half_rn(w[e]));
            stage[p] = make_uint2(((unsigned)src[e] << 16) | (unsigned)wh,
                                  (unsigned)(d - b * NPB));
        }
    }
}

// ---------------- MFMA fragment loads ----------------
__device__ inline f16x8 load_afrag_f32(const float* a) {
    float4 u0 = *(const float4*)a;
    float4 u1 = *(const float4*)(a + 4);
    f16x8 r;
    r[0] = (_Float16)u0.x; r[1] = (_Float16)u0.y; r[2] = (_Float16)u0.z; r[3] = (_Float16)u0.w;
    r[4] = (_Float16)u1.x; r[5] = (_Float16)u1.y; r[6] = (_Float16)u1.z; r[7] = (_Float16)u1.w;
    return r;
}

// one 128-row gemm tile from fp32 A, fragW in LDS (8 waves x 16 rows)
__device__ inline void gemm_tile_f32(const float* __restrict__ A, const _Float16* fragW,
                                     unsigned char* __restrict__ C, int blk, int tid) {
    const int lane = tid & 63;
    const int wid = tid >> 6;
    const int row0 = blk * 128 + wid * 16;
    if (row0 >= N_NODES) return;
    const int arow = row0 + (lane & 15);
    const int koff = (lane >> 4) << 3;
    f32x4 acc[8] = {};
#pragma unroll
    for (int kt = 0; kt < 4; ++kt) {
        f16x8 a = load_afrag_f32(A + (size_t)arow * DIM + kt * 32 + koff);
#pragma unroll
        for (int nt = 0; nt < 8; ++nt) {
            f16x8 b = *(const f16x8*)&fragW[(((nt << 2) | kt) << 9) | (lane << 3)];
            acc[nt] = __builtin_amdgcn_mfma_f32_16x16x32_f16(a, b, acc[nt], 0, 0, 0);
        }
    }
    const int crow = row0 + ((lane >> 4) << 2);
    const int ccol = lane & 15;
#pragma unroll
    for (int nt = 0; nt < 8; ++nt) {
#pragma unroll
        for (int r = 0; r < 4; ++r) {
            int v8 = __builtin_amdgcn_cvt_pk_fp8_f32(acc[nt][r], acc[nt][r], 0, false);
            C[(size_t)(crow + r) * DIM + (nt << 4) + ccol] = (unsigned char)(v8 & 0xff);
        }
    }
}

// ---------------- fused: gemm1 (blocks < MB) + bucket_build (blocks >= MB) -
#define MFMA_BLK ((N_NODES + 127) / 128)   // 391
__global__ __launch_bounds__(512) void gemm1_build(
        const float* __restrict__ A, const _Float16* __restrict__ fragWg,
        unsigned char* __restrict__ C, const int* __restrict__ gCur,
        const uint2* __restrict__ stage, unsigned int* __restrict__ pack,
        int2* __restrict__ range) {
    __shared__ __align__(16) _Float16 fragW[16384];   // 32 KB (gemm path)
    __shared__ int lhist[NPB];
    __shared__ int lincl[256];
    __shared__ int lcur[NPB];
    const int tid = threadIdx.x;
    if (blockIdx.x < MFMA_BLK) {
        for (int i = tid; i < 2048; i += 512)
            ((uint4*)fragW)[i] = ((const uint4*)fragWg)[i];
        __syncthreads();
        gemm_tile_f32(A, fragW, C, blockIdx.x, tid);
        return;
    }
    // ---- bucket_build path (512 threads, 8 items each) ----
    const int b = blockIdx.x - MFMA_BLK;
    const int t = tid;
    const int cnt = gCur[b];                 // zero-based cursors
    for (int i = t; i < NPB; i += 512) lhist[i] = 0;
    __syncthreads();
    unsigned myX[BCAP / 512];
    int myLd[BCAP / 512];
#pragma unroll
    for (int j = 0; j < BCAP / 512; ++j) {
        int i = j * 512 + t;
        if (i < cnt) {
            uint2 r = stage[b * BCAP + i];
            myX[j] = r.x;
            myLd[j] = (int)r.y;
            atomicAdd(&lhist[r.y], 1);
        } else {
            myLd[j] = -1;
        }
    }
    __syncthreads();
    int h = (t < NPB) ? lhist[t] : 0;
    if (t < 256) lincl[t] = h;
    __syncthreads();
    for (int off = 1; off < 256; off <<= 1) {
        int v = (t >= off && t < 256) ? lincl[t - off] : 0;
        __syncthreads();
        if (t < 256) lincl[t] += v;
        __syncthreads();
    }
    if (t < NPB) lcur[t] = lincl[t] - h;   // exclusive prefix
    __syncthreads();
#pragma unroll
    for (int j = 0; j < BCAP / 512; ++j) {
        if (myLd[j] >= 0) {
            int p = atomicAdd(&lcur[myLd[j]], 1);
            pack[b * BCAP + p] = myX[j];
        }
    }
    if (t < NPB) {
        int v = b * NPB + t;
        range[v] = make_int2(b * BCAP + lincl[t] - h, b * BCAP + lincl[t]);
    }
}

// ---------------- fused gather0 + gemm2 (R11 shape: 16 nodes/block) -------
__global__ __launch_bounds__(256) void gather_gemm2(
        const unsigned char* __restrict__ msg, const unsigned int* __restrict__ pack,
        const int2* __restrict__ range, const float* __restrict__ bias,
        const _Float16* __restrict__ fragW2, unsigned char* __restrict__ C) {
    __shared__ __align__(16) char hT[16 * 256];   // 16 rows x 128 fp16 (4 KB)
    const int t = threadIdx.x;
    const int grpL = t >> 4;       // local node 0..15
    const int lane16 = t & 15;
    const int tile = blockIdx.x;   // 3125 tiles x 16 nodes = 50000
    {
        const int grp = tile * 16 + grpL;
        int2 r = range[grp];
        int beg = r.x, end = r.y;
        float acc[8] = {};
        int i = beg;
        for (; i + 7 < end; i += 8) {
            unsigned p[8];
            uint2 q[8];
#pragma unroll
            for (int j = 0; j < 8; ++j) p[j] = pack[i + j];
#pragma unroll
            for (int j = 0; j < 8; ++j)
                q[j] = ((const uint2*)(msg + (size_t)(p[j] >> 16) * DIM))[lane16];
#pragma unroll
            for (int j = 0; j < 8; ++j) accrow(q[j], wgt(p[j]), acc);
        }
        for (; i + 3 < end; i += 4) {
            unsigned p0 = pack[i], p1 = pack[i + 1], p2 = pack[i + 2], p3 = pack[i + 3];
            uint2 q0 = ((const uint2*)(msg + (size_t)(p0 >> 16) * DIM))[lane16];
            uint2 q1 = ((const uint2*)(msg + (size_t)(p1 >> 16) * DIM))[lane16];
            uint2 q2 = ((const uint2*)(msg + (size_t)(p2 >> 16) * DIM))[lane16];
            uint2 q3 = ((const uint2*)(msg + (size_t)(p3 >> 16) * DIM))[lane16];
            accrow(q0, wgt(p0), acc);
            accrow(q1, wgt(p1), acc);
            accrow(q2, wgt(p2), acc);
            accrow(q3, wgt(p3), acc);
        }
        for (; i < end; ++i) {
            unsigned p = pack[i];
            uint2 q = ((const uint2*)(msg + (size_t)(p >> 16) * DIM))[lane16];
            accrow(q, wgt(p), acc);
        }
        float4 b0 = ((const float4*)bias)[2 * lane16];
        float4 b1 = ((const float4*)bias)[2 * lane16 + 1];
        union { __half2 h[4]; uint4 u; } o;
        o.h[0] = __floats2half2_rn(fmaxf(acc[0] + b0.x, 0.f), fmaxf(acc[1] + b0.y, 0.f));
        o.h[1] = __floats2half2_rn(fmaxf(acc[2] + b0.z, 0.f), fmaxf(acc[3] + b0.w, 0.f));
        o.h[2] = __floats2half2_rn(fmaxf(acc[4] + b1.x, 0.f), fmaxf(acc[5] + b1.y, 0.f));
        o.h[3] = __floats2half2_rn(fmaxf(acc[6] + b1.z, 0.f), fmaxf(acc[7] + b1.w, 0.f));
        int boff = (grpL << 8) | (lane16 << 4);
        boff ^= (grpL & 7) << 4;              // XOR swizzle (G4)
        *(uint4*)(hT + boff) = o.u;
    }
    __syncthreads();
    // ---- MFMA phase: wave wid handles nt = 2*wid, 2*wid+1 ----
    const int lane = t & 63;
    const int wid = t >> 6;
    const int arowL = lane & 15;
    const int koff = (lane >> 4) << 3;
    f32x4 acc2[2] = {};
#pragma unroll
    for (int kt = 0; kt < 4; ++kt) {
        int boff = (arowL << 8) | ((kt * 32 + koff) << 1);
        boff ^= (arowL & 7) << 4;
        f16x8 a = *(const f16x8*)(hT + boff);
#pragma unroll
        for (int n = 0; n < 2; ++n) {
            int nt = wid * 2 + n;
            f16x8 b = *(const f16x8*)&fragW2[(((nt << 2) | kt) << 9) | (lane << 3)];
            acc2[n] = __builtin_amdgcn_mfma_f32_16x16x32_f16(a, b, acc2[n], 0, 0, 0);
        }
    }
    const int crow = tile * 16 + ((lane >> 4) << 2);
    const int ccol = lane & 15;
#pragma unroll
    for (int n = 0; n < 2; ++n) {
#pragma unroll
        for (int r = 0; r < 4; ++r) {
            int v8 = __builtin_amdgcn_cvt_pk_fp8_f32(acc2[n][r], acc2[n][r], 0, false);
            C[(size_t)(crow + r) * DIM + ((wid * 2 + n) << 4) + ccol] = (unsigned char)(v8 & 0xff);
        }
    }
}

// ---------------- gather1: s = relu(A(h1@W2)+b2) @ Wf ----------------
__global__ void gather_wf(const unsigned char* __restrict__ msg,
                          const unsigned int* __restrict__ pack,
                          const int2* __restrict__ range, const float* __restrict__ bias,
                          const float* __restrict__ wf, float* __restrict__ outS) {
    int gid = blockIdx.x * blockDim.x + threadIdx.x;
    int grp = gid >> 4, lane = gid & 15;
    if (grp >= N_NODES) return;
    int2 r = range[grp];
    int beg = r.x, end = r.y;
    float acc[8] = {};
    int i = beg;
    for (; i + 7 < end; i += 8) {
        unsigned p[8];
        uint2 q[8];
#pragma unroll
        for (int j = 0; j < 8; ++j) p[j] = pack[i + j];
#pragma unroll
        for (int j = 0; j < 8; ++j)
            q[j] = ((const uint2*)(msg + (size_t)(p[j] >> 16) * DIM))[lane];
#pragma unroll
        for (int j = 0; j < 8; ++j) accrow(q[j], wgt(p[j]), acc);
    }
    for (; i + 3 < end; i += 4) {
        unsigned p0 = pack[i], p1 = pack[i + 1], p2 = pack[i + 2], p3 = pack[i + 3];
        uint2 q0 = ((const uint2*)(msg + (size_t)(p0 >> 16) * DIM))[lane];
        uint2 q1 = ((const uint2*)(msg + (size_t)(p1 >> 16) * DIM))[lane];
        uint2 q2 = ((const uint2*)(msg + (size_t)(p2 >> 16) * DIM))[lane];
        uint2 q3 = ((const uint2*)(msg + (size_t)(p3 >> 16) * DIM))[lane];
        accrow(q0, wgt(p0), acc);
        accrow(q1, wgt(p1), acc);
        accrow(q2, wgt(p2), acc);
        accrow(q3, wgt(p3), acc);
    }
    for (; i < end; ++i) {
        unsigned p = pack[i];
        uint2 q = ((const uint2*)(msg + (size_t)(p >> 16) * DIM))[lane];
        accrow(q, wgt(p), acc);
    }
    float4 b0 = ((const float4*)bias)[2 * lane];
    float4 b1 = ((const float4*)bias)[2 * lane + 1];
    float4 f0 = ((const float4*)wf)[2 * lane];
    float4 f1 = ((const float4*)wf)[2 * lane + 1];
    float d = fmaxf(acc[0] + b0.x, 0.f) * f0.x + fmaxf(acc[1] + b0.y, 0.f) * f0.y
            + fmaxf(acc[2] + b0.z, 0.f) * f0.z + fmaxf(acc[3] + b0.w, 0.f) * f0.w
            + fmaxf(acc[4] + b1.x, 0.f) * f1.x + fmaxf(acc[5] + b1.y, 0.f) * f1.y
            + fmaxf(acc[6] + b1.z, 0.f) * f1.z + fmaxf(acc[7] + b1.w, 0.f) * f1.w;
#pragma unroll
    for (int off = 8; off; off >>= 1) d += __shfl_down(d, off, 16);
    if (lane == 0) outS[grp] = d;
}

// ---------------- fused final aggregation + per-graph readout -------------
__global__ void final_readout(const float* __restrict__ s, const unsigned int* __restrict__ pack,
                              const int2* __restrict__ range, const float* __restrict__ bfp,
                              float* __restrict__ out) {
    __shared__ float red[256];
    int g = blockIdx.x;
    float bf = bfp[0];
    float sum = 0.f;
    for (int n = threadIdx.x; n < NPG; n += blockDim.x) {
        int v = g * NPG + n;
        int2 r = range[v];
        float a = 0.f;
        for (int i = r.x; i < r.y; ++i) {
            unsigned int p = pack[i];
            a += wgt(p) * s[p >> 16];
        }
        a += bf;
        sum += 1.f / (1.f + expf(-a));
    }
    red[threadIdx.x] = sum;
    __syncthreads();
    for (int t = 128; t > 0; t >>= 1) {
        if (threadIdx.x < t) red[threadIdx.x] += red[threadIdx.x + t];
        __syncthreads();
    }
    if (threadIdx.x == 0) out[g] = red[0] / (float)NPG;
}

extern "C" void kernel_launch(void* const* d_in, const int* in_sizes, int n_in,
                              void* d_out, int out_size, void* d_ws, size_t ws_size,
                              hipStream_t stream) {
    const float* X  = (const float*)d_in[0];
    const float* ew = (const float*)d_in[1];
    const float* W1 = (const float*)d_in[2];
    const float* b1 = (const float*)d_in[3];
    const float* W2 = (const float*)d_in[4];
    const float* b2 = (const float*)d_in[5];
    const float* Wf = (const float*)d_in[6];
    const float* bf = (const float*)d_in[7];
    const int* ei   = (const int*)d_in[8];
    const int* src  = ei;
    const int* dst  = ei + NEDGE;

    float* out = (float*)d_out;

    // workspace layout
    char* ws = (char*)d_ws;
    size_t off = 0;
    unsigned char* bufA = (unsigned char*)(ws + off); off += (size_t)N_NODES * DIM;  // 6.4 MB
    unsigned char* bufB = (unsigned char*)(ws + off); off += (size_t)N_NODES * DIM;  // 6.4 MB
    uint2* stage = (uint2*)(ws + off);  off += (size_t)NBUCKET * BCAP * 8;           // 8 MB
    unsigned int* pack = (unsigned int*)(ws + off); off += (size_t)NBUCKET * BCAP * 4; // 4 MB
    int2* range = (int2*)(ws + off);    off += (size_t)N_NODES * 8;                  // 400 KB
    int* gCur   = (int*)(ws + off);     off += (size_t)256 * 4;
    _Float16* fragW1 = (_Float16*)(ws + off); off += (size_t)16384 * 2;              // 32 KB
    _Float16* fragW2 = (_Float16*)(ws + off); off += (size_t)16384 * 2;              // 32 KB
    float* s_node = (float*)(ws + off); off += (size_t)N_NODES * 4;

    const int TB = 256;
    const int TILE_BLK = N_NODES / 16;                    // 3125
    const int GATHER_BLK = (N_NODES * 16 + TB - 1) / TB;  // 3125

    // ---- cursor zero + fused scatter/fragW-prep ----
    hipMemsetAsync(gCur, 0, (size_t)NBUCKET * 4, stream);
    scatter_prep<<<SCAT_BLK + 128, TB, 0, stream>>>(src, dst, ew, gCur, stage,
                                                    W1, W2, fragW1, fragW2, NEDGE);
    // ---- layer-1 GEMM fused with CSR pass 2 (independent work) ----
    gemm1_build<<<MFMA_BLK + NBUCKET, 512, 0, stream>>>(X, fragW1, bufA, gCur,
                                                        stage, pack, range);
    // ---- fused: gather0 (h1) + gemm2 (h1@W2 -> bufB fp8) ----
    gather_gemm2<<<TILE_BLK, TB, 0, stream>>>(bufA, pack, range, b1, fragW2, bufB);
    // ---- gather1 + Wf dot -> s_node ----
    gather_wf<<<GATHER_BLK, TB, 0, stream>>>(bufB, pack, range, b2, Wf, s_node);
    // ---- final aggregation + readout (fused) ----
    final_readout<<<NGRAPH, TB, 0, stream>>>(s_node, pack, range, bf, out);
}